// Round 3
// baseline (7513.771 us; speedup 1.0000x reference)
//
#include <hip/hip_runtime.h>

// ---------------- problem dims (fixed by setup_inputs) ----------------
#define B_    4
#define T_    4096
#define DD_   1024
#define N_    1024
#define K3_   3072
#define M_    16384      // B_*T_
#define CL_   64         // scan chunk length (time steps)
#define NCHK_ (M_/CL_)   // 256 global chunks (64 per batch)
#define SROWS_ 2048      // stripe rows
#define NSTRIPE_ (M_/SROWS_)   // 8

// ---------------- ws layout (float offsets), total ~48 MiB ----------------
#define OFF_RAWS ((size_t)0)                         // SROWS_*K3_  (24 MiB)
#define OFF_USS  (OFF_RAWS + (size_t)SROWS_*K3_)     // SROWS_*N_   (8 MiB)
#define OFF_G0   (OFF_USS  + (size_t)SROWS_*N_)      // N_*N_
#define OFF_P    (OFF_G0   + (size_t)N_*N_)
#define OFF_Q    (OFF_P    + (size_t)N_*N_)
#define OFF_AGA  (OFF_Q    + (size_t)N_*N_)          // NCHK_*N_
#define OFF_AGB  (OFF_AGA  + (size_t)NCHK_*N_)
#define OFF_PRE  (OFF_AGB  + (size_t)NCHK_*N_)
#define OFF_V0   (OFF_PRE  + (size_t)NCHK_*N_)
#define OFF_W1   (OFF_V0   + N_)
#define OFF_W2   (OFF_W1   + N_)
#define OFF_SC   (OFF_W2   + N_)   // [0]=trace scratch, [1]=inv_scale_in, [2]=inv_scale_out
#define REQ_FLOATS (OFF_SC + 4)

// ---------------- fallback: zero d_out (diagnostic if ws too small) --------
__global__ void zero_out(float* __restrict__ y, int n)
{
    int i = blockIdx.x * 256 + threadIdx.x;
    if (i < n) y[i] = 0.f;
}

// =====================================================================
// NT GEMM, 128x128 tile, BK=16, 256 threads, 8x8 micro (2x2 of 4x4).
// C[m,n] = scale * sum_k A[m,k]*B[n,k].
// =====================================================================
__global__ __launch_bounds__(256, 2) void gemm_nt_128(
    const float* __restrict__ A, const float* __restrict__ Bm,
    float* __restrict__ C, int K, int ldc, const float* __restrict__ scale_ptr)
{
    __shared__ float As[16][132];
    __shared__ float Bs[16][132];
    const int tid = threadIdx.x;
    const int m0 = blockIdx.y * 128;
    const int n0 = blockIdx.x * 128;
    const int lr = tid >> 2;          // 0..63
    const int lq = (tid & 3) << 2;    // 0,4,8,12
    const float* Ag = A  + (size_t)(m0 + lr) * K + lq;
    const float* Bg = Bm + (size_t)(n0 + lr) * K + lq;
    const int tx = tid & 15;
    const int ty = tid >> 4;

    float acc[2][2][4][4];
    #pragma unroll
    for (int h = 0; h < 2; ++h)
      #pragma unroll
      for (int g = 0; g < 2; ++g)
        #pragma unroll
        for (int i = 0; i < 4; ++i)
          #pragma unroll
          for (int j = 0; j < 4; ++j) acc[h][g][i][j] = 0.f;

    float4 a0 = *(const float4*)(Ag);
    float4 a1 = *(const float4*)(Ag + (size_t)64 * K);
    float4 b0 = *(const float4*)(Bg);
    float4 b1 = *(const float4*)(Bg + (size_t)64 * K);

    for (int kt = 0; kt < K; kt += 16) {
        __syncthreads();
        As[lq+0][lr]    = a0.x; As[lq+1][lr]    = a0.y; As[lq+2][lr]    = a0.z; As[lq+3][lr]    = a0.w;
        As[lq+0][64+lr] = a1.x; As[lq+1][64+lr] = a1.y; As[lq+2][64+lr] = a1.z; As[lq+3][64+lr] = a1.w;
        Bs[lq+0][lr]    = b0.x; Bs[lq+1][lr]    = b0.y; Bs[lq+2][lr]    = b0.z; Bs[lq+3][lr]    = b0.w;
        Bs[lq+0][64+lr] = b1.x; Bs[lq+1][64+lr] = b1.y; Bs[lq+2][64+lr] = b1.z; Bs[lq+3][64+lr] = b1.w;
        __syncthreads();
        if (kt + 16 < K) {
            a0 = *(const float4*)(Ag + kt + 16);
            a1 = *(const float4*)(Ag + kt + 16 + (size_t)64 * K);
            b0 = *(const float4*)(Bg + kt + 16);
            b1 = *(const float4*)(Bg + kt + 16 + (size_t)64 * K);
        }
        #pragma unroll
        for (int k = 0; k < 16; ++k) {
            float4 av0 = *(const float4*)&As[k][ty*4];
            float4 av1 = *(const float4*)&As[k][64 + ty*4];
            float4 bv0 = *(const float4*)&Bs[k][tx*4];
            float4 bv1 = *(const float4*)&Bs[k][64 + tx*4];
            float av[2][4] = {{av0.x,av0.y,av0.z,av0.w},{av1.x,av1.y,av1.z,av1.w}};
            float bv[2][4] = {{bv0.x,bv0.y,bv0.z,bv0.w},{bv1.x,bv1.y,bv1.z,bv1.w}};
            #pragma unroll
            for (int h = 0; h < 2; ++h)
              #pragma unroll
              for (int i = 0; i < 4; ++i)
                #pragma unroll
                for (int g = 0; g < 2; ++g)
                  #pragma unroll
                  for (int j = 0; j < 4; ++j)
                      acc[h][g][i][j] = fmaf(av[h][i], bv[g][j], acc[h][g][i][j]);
        }
    }
    const float sc = scale_ptr ? scale_ptr[0] : 1.0f;
    #pragma unroll
    for (int h = 0; h < 2; ++h)
      #pragma unroll
      for (int i = 0; i < 4; ++i) {
        const int row = m0 + h*64 + ty*4 + i;
        float* cp = C + (size_t)row * ldc + n0;
        #pragma unroll
        for (int g = 0; g < 2; ++g) {
            float4 v;
            v.x = acc[h][g][i][0]*sc; v.y = acc[h][g][i][1]*sc;
            v.z = acc[h][g][i][2]*sc; v.w = acc[h][g][i][3]*sc;
            *(float4*)(cp + g*64 + tx*4) = v;
        }
    }
}

// =====================================================================
// NT GEMM, 64x64 tile, BK=32 (1024x1024 sigma gemms).
// mode: 0 none, 2 multiply by 1/(s*s)
// =====================================================================
__global__ __launch_bounds__(256, 4) void gemm_nt_64(
    const float* __restrict__ A, const float* __restrict__ Bm,
    float* __restrict__ C, int K, int ldc,
    const float* __restrict__ sptr, int mode)
{
    __shared__ float As[32][68];
    __shared__ float Bs[32][68];
    const int tid = threadIdx.x;
    const int m0 = blockIdx.y * 64;
    const int n0 = blockIdx.x * 64;
    const int lr = tid >> 3;
    const int lq = (tid & 7) << 2;
    const float* Ag = A  + (size_t)(m0 + lr) * K + lq;
    const float* Bg = Bm + (size_t)(n0 + lr) * K + lq;
    const int tx = tid & 15;
    const int ty = tid >> 4;

    float acc[4][4];
    #pragma unroll
    for (int i = 0; i < 4; ++i)
      #pragma unroll
      for (int j = 0; j < 4; ++j) acc[i][j] = 0.f;

    float4 a0 = *(const float4*)(Ag);
    float4 a1 = *(const float4*)(Ag + (size_t)32 * K);
    float4 b0 = *(const float4*)(Bg);
    float4 b1 = *(const float4*)(Bg + (size_t)32 * K);

    for (int kt = 0; kt < K; kt += 32) {
        __syncthreads();
        As[lq+0][lr]    = a0.x; As[lq+1][lr]    = a0.y; As[lq+2][lr]    = a0.z; As[lq+3][lr]    = a0.w;
        As[lq+0][32+lr] = a1.x; As[lq+1][32+lr] = a1.y; As[lq+2][32+lr] = a1.z; As[lq+3][32+lr] = a1.w;
        Bs[lq+0][lr]    = b0.x; Bs[lq+1][lr]    = b0.y; Bs[lq+2][lr]    = b0.z; Bs[lq+3][lr]    = b0.w;
        Bs[lq+0][32+lr] = b1.x; Bs[lq+1][32+lr] = b1.y; Bs[lq+2][32+lr] = b1.z; Bs[lq+3][32+lr] = b1.w;
        __syncthreads();
        if (kt + 32 < K) {
            a0 = *(const float4*)(Ag + kt + 32);
            a1 = *(const float4*)(Ag + kt + 32 + (size_t)32 * K);
            b0 = *(const float4*)(Bg + kt + 32);
            b1 = *(const float4*)(Bg + kt + 32 + (size_t)32 * K);
        }
        #pragma unroll
        for (int k = 0; k < 32; ++k) {
            float4 av = *(const float4*)&As[k][ty*4];
            float4 bv = *(const float4*)&Bs[k][tx*4];
            float avf[4] = {av.x,av.y,av.z,av.w};
            float bvf[4] = {bv.x,bv.y,bv.z,bv.w};
            #pragma unroll
            for (int i = 0; i < 4; ++i)
              #pragma unroll
              for (int j = 0; j < 4; ++j)
                  acc[i][j] = fmaf(avf[i], bvf[j], acc[i][j]);
        }
    }
    float sc = 1.0f;
    if (mode == 2) { float s = sptr[0]; sc = 1.0f / (s * s); }
    #pragma unroll
    for (int i = 0; i < 4; ++i) {
        const int row = m0 + ty*4 + i;
        float4 v;
        v.x = acc[i][0]*sc; v.y = acc[i][1]*sc; v.z = acc[i][2]*sc; v.w = acc[i][3]*sc;
        *(float4*)(C + (size_t)row * ldc + n0 + tx*4) = v;
    }
}

// ---------------- trace of 1024x1024 (1 block) ----------------
__global__ void trace_diag(const float* __restrict__ A, float* __restrict__ out)
{
    __shared__ float red[256];
    const int tid = threadIdx.x;
    float s = 0.f;
    for (int i = tid; i < N_; i += 256) s += A[(size_t)i * (N_ + 1)];
    red[tid] = s; __syncthreads();
    for (int off = 128; off > 0; off >>= 1) {
        if (tid < off) red[tid] += red[tid + off];
        __syncthreads();
    }
    if (tid == 0) out[0] = red[0];
}

// ---- pick column with max diagonal (dominant-eigvec seed) ----
__global__ void pick_col(const float* __restrict__ P, float* __restrict__ v)
{
    __shared__ float sval[256];
    __shared__ int   sidx[256];
    __shared__ int   jstar;
    const int tid = threadIdx.x;
    float best = -1.f; int bidx = 0;
    for (int i = tid; i < N_; i += 256) {
        float d = P[(size_t)i * (N_ + 1)];
        if (d > best) { best = d; bidx = i; }
    }
    sval[tid] = best; sidx[tid] = bidx; __syncthreads();
    for (int off = 128; off > 0; off >>= 1) {
        if (tid < off && sval[tid + off] > sval[tid]) {
            sval[tid] = sval[tid + off]; sidx[tid] = sidx[tid + off];
        }
        __syncthreads();
    }
    if (tid == 0) jstar = sidx[0];
    __syncthreads();
    const int j = jstar;
    for (int i = tid; i < N_; i += 256) v[i] = P[(size_t)j * N_ + i];
}

// ---------------- w = G * v (one wave per row) ----------------
__global__ __launch_bounds__(256) void matvec_1024(
    const float* __restrict__ G, const float* __restrict__ v, float* __restrict__ w)
{
    const int row  = blockIdx.x * 4 + (threadIdx.x >> 6);
    const int lane = threadIdx.x & 63;
    const float* g = G + (size_t)row * N_;
    float s = 0.f;
    for (int j = lane; j < N_; j += 64) s += g[j] * v[j];
    #pragma unroll
    for (int off = 32; off > 0; off >>= 1) s += __shfl_down(s, off, 64);
    if (lane == 0) w[row] = s;
}

// ------- Rayleigh quotient -> inv_scale = 1/max(sigma,1) -------
__global__ void rq_scale(const float* __restrict__ w1, const float* __restrict__ w2,
                         float* __restrict__ slot)
{
    __shared__ float r11[256];
    __shared__ float r12[256];
    const int tid = threadIdx.x;
    float d11 = 0.f, d12 = 0.f;
    for (int i = tid; i < N_; i += 256) {
        float a = w1[i], b = w2[i];
        d11 = fmaf(a, a, d11);
        d12 = fmaf(a, b, d12);
    }
    r11[tid] = d11; r12[tid] = d12; __syncthreads();
    for (int off = 128; off > 0; off >>= 1) {
        if (tid < off) { r11[tid] += r11[tid + off]; r12[tid] += r12[tid + off]; }
        __syncthreads();
    }
    if (tid == 0) {
        float lam = r12[0] / fmaxf(r11[0], 1e-30f);
        float sig = sqrtf(fmaxf(lam, 0.f));
        slot[0] = 1.0f / fmaxf(sig, 1.0f);
    }
}

// ---------------- fused elementwise math ----------------
__device__ __forceinline__ float softplusf(float x)
{
    return fmaxf(x, 0.f) + log1pf(expf(-fabsf(x)));
}

__device__ __forceinline__ void abc_math(
    float dr, float br, float cr, float uval,
    float alpha, float db, float sgain,
    float* pa, float* pbu, float* pc)
{
    float delta = softplusf(dr + db);
    float a = fminf(expf(-delta * alpha), 1.0f - 1e-4f);
    float b = tanhf(br);
    float c = tanhf(cr);
    float p = fmaf(a, a, c * c);
    float r = b * b;
    float q = a * b;
    float pr = p - r;
    float disc = fmaf(pr, pr, 4.0f * q * q);
    float lam = 0.5f * (p + r + sqrtf(disc + 1e-12f));
    float sig = sqrtf(lam + 1e-12f);
    float inv = 1.0f / fmaxf(sig, 1.0f);
    a *= inv; b *= inv; c *= inv;
    *pa = a; *pc = c; *pbu = b * (sgain * uval);
}

// --------- scan phase 1 (per stripe): per-chunk composite ---------
// rawS (SROWS_ x K3_) and usS (SROWS_ x N_) are stripe-local; r0 = first
// global row of the stripe (multiple of SROWS_).
__global__ __launch_bounds__(256) void scan_phase1(
    const float* __restrict__ rawS, const float* __restrict__ usS,
    const float* __restrict__ bp, const float* __restrict__ dbias,
    const float* __restrict__ alog, const float* __restrict__ lgam,
    const float* __restrict__ inv_sin,
    float* __restrict__ agg_a, float* __restrict__ agg_b, int r0)
{
    const int gid = blockIdx.x * 256 + threadIdx.x;   // [0, (SROWS_/CL_)*N_)
    const int n   = gid & (N_ - 1);
    const int cl  = gid >> 10;                        // local chunk 0..31
    const int gchunk = (r0 >> 6) + cl;

    const float alpha = softplusf(alog[n]);
    const float db    = dbias[n];
    const float bpd   = bp[n];
    const float bpb   = bp[N_ + n];
    const float bpc   = bp[2*N_ + n];
    const float sgain = expf(lgam[0]) * inv_sin[0];

    float Ap = 1.f, Bc = 0.f;
    size_t base  = (size_t)(cl * CL_) * K3_ + n;      // stripe-local
    size_t ubase = (size_t)(cl * CL_) * N_  + n;      // stripe-local
    for (int j = 0; j < CL_; ++j) {
        float dr = rawS[base]        + bpd;
        float br = rawS[base + N_]   + bpb;
        float cr = rawS[base + 2*N_] + bpc;
        float uv = usS[ubase];
        float a, bu, cv;
        abc_math(dr, br, cr, uv, alpha, db, sgain, &a, &bu, &cv);
        Bc = fmaf(a, Bc, bu);
        Ap *= a;
        base += K3_; ubase += N_;
    }
    agg_a[(size_t)gchunk * N_ + n] = Ap;
    agg_b[(size_t)gchunk * N_ + n] = Bc;
}

// --------- scan phase 2: exclusive scan over chunk aggregates (per batch) ---------
__global__ void scan_phase2(const float* __restrict__ agg_a,
                            const float* __restrict__ agg_b,
                            float* __restrict__ pref)
{
    const int gid = blockIdx.x * 256 + threadIdx.x;   // 0..B*N-1
    const int n = gid & (N_ - 1);
    const int b = gid >> 10;
    float z = 0.f;
    size_t idx = (size_t)(b * (T_/CL_)) * N_ + n;     // 64 chunks per batch
    for (int c = 0; c < T_/CL_; ++c) {
        pref[idx] = z;
        z = fmaf(agg_a[idx], z, agg_b[idx]);
        idx += N_;
    }
}

// --------- scan phase 3 (per stripe): replay with carry, y_hat over usS ---------
__global__ __launch_bounds__(256) void scan_phase3(
    const float* __restrict__ rawS, float* __restrict__ usS,
    const float* __restrict__ bp, const float* __restrict__ dbias,
    const float* __restrict__ alog, const float* __restrict__ lgam,
    const float* __restrict__ inv_sin, const float* __restrict__ pref, int r0)
{
    const int gid = blockIdx.x * 256 + threadIdx.x;
    const int n   = gid & (N_ - 1);
    const int cl  = gid >> 10;
    const int gchunk = (r0 >> 6) + cl;

    const float alpha = softplusf(alog[n]);
    const float db    = dbias[n];
    const float bpd   = bp[n];
    const float bpb   = bp[N_ + n];
    const float bpc   = bp[2*N_ + n];
    const float sgain = expf(lgam[0]) * inv_sin[0];

    float z = pref[(size_t)gchunk * N_ + n];
    size_t base  = (size_t)(cl * CL_) * K3_ + n;
    size_t ubase = (size_t)(cl * CL_) * N_  + n;
    for (int j = 0; j < CL_; ++j) {
        float dr = rawS[base]        + bpd;
        float br = rawS[base + N_]   + bpb;
        float cr = rawS[base + 2*N_] + bpc;
        float uv = usS[ubase];
        float a, bu, cv;
        abc_math(dr, br, cr, uv, alpha, db, sgain, &a, &bu, &cv);
        usS[ubase] = cv * z;          // y_hat[t] uses pre-update state
        z = fmaf(a, z, bu);
        base += K3_; ubase += N_;
    }
}

// =====================================================================
extern "C" void kernel_launch(void* const* d_in, const int* in_sizes, int n_in,
                              void* d_out, int out_size, void* d_ws, size_t ws_size,
                              hipStream_t stream)
{
    (void)in_sizes; (void)n_in;
    const float* u     = (const float*)d_in[0];
    const float* W_in  = (const float*)d_in[1];
    const float* W_out = (const float*)d_in[2];
    const float* Wp    = (const float*)d_in[3];
    const float* bp    = (const float*)d_in[4];
    const float* alog  = (const float*)d_in[5];
    const float* dbias = (const float*)d_in[6];
    const float* lgam  = (const float*)d_in[7];
    float* y = (float*)d_out;

    // Diagnostic fallback: if workspace is smaller than our layout, do NOT
    // touch it (avoid GPU fault). Zero the output instead -> bench reports
    // absmax ~= 0.42 (max|ref|), which tells us ws_size < 48 MiB.
    if (ws_size < (size_t)REQ_FLOATS * sizeof(float)) {
        zero_out<<<(out_size + 255) / 256, dim3(256), 0, stream>>>(y, out_size);
        return;
    }

    float* ws    = (float*)d_ws;
    float* rawS  = ws + OFF_RAWS;
    float* usS   = ws + OFF_USS;
    float* G0    = ws + OFF_G0;
    float* Pb    = ws + OFF_P;
    float* Qb    = ws + OFF_Q;
    float* agg_a = ws + OFF_AGA;
    float* agg_b = ws + OFF_AGB;
    float* pref  = ws + OFF_PRE;
    float* v0    = ws + OFF_V0;
    float* w1    = ws + OFF_W1;
    float* w2    = ws + OFF_W2;
    float* scal  = ws + OFF_SC;

    const dim3 blk(256);
    const dim3 g64(16, 16);

    // ---- spectral norms: gram + 8 trace-normalized squarings + RQ ----
    auto sigma_pipeline = [&](const float* W, float* slot) {
        gemm_nt_64<<<g64, blk, 0, stream>>>(W, W, G0, 1024, 1024, nullptr, 0);
        const float* src = G0;
        float* dst = Pb;
        for (int i = 0; i < 8; ++i) {
            trace_diag<<<1, blk, 0, stream>>>(src, scal + 0);
            gemm_nt_64<<<g64, blk, 0, stream>>>(src, src, dst, 1024, 1024, scal + 0, 2);
            src = dst;
            dst = (dst == Pb) ? Qb : Pb;
        }
        pick_col<<<1, blk, 0, stream>>>(src, v0);
        matvec_1024<<<256, blk, 0, stream>>>(G0, v0, w1);
        matvec_1024<<<256, blk, 0, stream>>>(G0, w1, w2);
        rq_scale<<<1, blk, 0, stream>>>(w1, w2, slot);
    };
    sigma_pipeline(W_in,  scal + 1);   // inv_scale_in
    sigma_pipeline(W_out, scal + 2);   // inv_scale_out

    const int sblocks = (SROWS_/CL_) * N_ / 256;   // 128 blocks per stripe

    // ---- pass A: per stripe, usS & rawS gemms, then chunk aggregates ----
    for (int s = 0; s < NSTRIPE_; ++s) {
        const int r0 = s * SROWS_;
        gemm_nt_128<<<dim3(8, SROWS_/128), blk, 0, stream>>>(
            u + (size_t)r0 * DD_, W_in, usS, 1024, 1024, nullptr);
        gemm_nt_128<<<dim3(24, SROWS_/128), blk, 0, stream>>>(
            u + (size_t)r0 * DD_, Wp, rawS, 1024, 3072, nullptr);
        scan_phase1<<<sblocks, blk, 0, stream>>>(rawS, usS, bp, dbias, alog, lgam,
                                                 scal + 1, agg_a, agg_b, r0);
    }

    // ---- chunk-prefix scan (per batch) ----
    scan_phase2<<<(B_*N_)/256, blk, 0, stream>>>(agg_a, agg_b, pref);

    // ---- pass B: per stripe, recompute, replay scan, y stripe out ----
    for (int s = 0; s < NSTRIPE_; ++s) {
        const int r0 = s * SROWS_;
        gemm_nt_128<<<dim3(8, SROWS_/128), blk, 0, stream>>>(
            u + (size_t)r0 * DD_, W_in, usS, 1024, 1024, nullptr);
        gemm_nt_128<<<dim3(24, SROWS_/128), blk, 0, stream>>>(
            u + (size_t)r0 * DD_, Wp, rawS, 1024, 3072, nullptr);
        scan_phase3<<<sblocks, blk, 0, stream>>>(rawS, usS, bp, dbias, alog, lgam,
                                                 scal + 1, pref, r0);
        gemm_nt_128<<<dim3(8, SROWS_/128), blk, 0, stream>>>(
            usS, W_out, y + (size_t)r0 * N_, 1024, 1024, scal + 2);
    }
}

// Round 4
// 2610.976 us; speedup vs baseline: 2.8778x; 2.8778x over previous
//
#include <hip/hip_runtime.h>

// ---------------- problem dims (fixed by setup_inputs) ----------------
#define B_    4
#define T_    4096
#define DD_   1024
#define N_    1024
#define K3_   3072
#define M_    16384      // B_*T_
#define CL_   64         // scan chunk length (time steps)
#define NCHK_ (M_/CL_)   // 256 global chunks (64 per batch)
#define SROWS_ 2048      // stripe rows
#define NSTRIPE_ (M_/SROWS_)   // 8

// ---------------- ws layout (float offsets), total ~48 MiB ----------------
#define OFF_RAWS ((size_t)0)                         // SROWS_*K3_  (24 MiB)
#define OFF_USS  (OFF_RAWS + (size_t)SROWS_*K3_)     // SROWS_*N_   (8 MiB)
#define OFF_G0   (OFF_USS  + (size_t)SROWS_*N_)      // N_*N_
#define OFF_P    (OFF_G0   + (size_t)N_*N_)
#define OFF_Q    (OFF_P    + (size_t)N_*N_)
#define OFF_AGA  (OFF_Q    + (size_t)N_*N_)          // NCHK_*N_
#define OFF_AGB  (OFF_AGA  + (size_t)NCHK_*N_)
#define OFF_PRE  (OFF_AGB  + (size_t)NCHK_*N_)
#define OFF_V0   (OFF_PRE  + (size_t)NCHK_*N_)
#define OFF_W1   (OFF_V0   + N_)
#define OFF_W2   (OFF_W1   + N_)
#define OFF_SC   (OFF_W2   + N_)   // [0]=trace scratch, [1]=inv_scale_in, [2]=inv_scale_out
#define REQ_FLOATS (OFF_SC + 4)

typedef short s8v __attribute__((ext_vector_type(8)));   // 8 bf16 in 4 VGPRs
typedef float f4v __attribute__((ext_vector_type(4)));   // MFMA acc

// fp32 -> bf16 round-to-nearest-even
__device__ __forceinline__ unsigned short f2bf(float f)
{
    unsigned u = __float_as_uint(f);
    u += 0x7FFFu + ((u >> 16) & 1u);
    return (unsigned short)(u >> 16);
}

// ---------------- fallback: zero d_out (diagnostic if ws too small) --------
__global__ void zero_out(float* __restrict__ y, int n)
{
    int i = blockIdx.x * 256 + threadIdx.x;
    if (i < n) y[i] = 0.f;
}

// =====================================================================
// bf16 MFMA NT GEMM, 128x128 tile, BK=32, 256 thr (4 waves, 64x64 each,
// 4x4 of 16x16x32 mfma). Reads fp32 global, converts to bf16 into LDS.
// Dual-output: block col n0g < nsplit -> B0/C0/ldc0, else B1/C1/ldc1
// (col offset n0g-nsplit). mode: 0 none, 1 *s[0], 2 *1/(s[0]^2).
// LDS row stride 40 shorts (80 B): b128 frag reads = optimal 2-phase.
// =====================================================================
__global__ __launch_bounds__(256, 2) void gemm_bf16_nt(
    const float* __restrict__ A,
    const float* __restrict__ B0, const float* __restrict__ B1,
    float* __restrict__ C0, float* __restrict__ C1,
    int K, int ldc0, int ldc1, int nsplit,
    const float* __restrict__ sptr, int mode)
{
    __shared__ __align__(16) short As[128 * 40];
    __shared__ __align__(16) short Bs[128 * 40];
    const int tid = threadIdx.x;
    const int m0  = blockIdx.y * 128;
    const int n0g = blockIdx.x * 128;

    const float* Bsrc; float* Cp; int ldc; int c0;
    if (n0g < nsplit) { Bsrc = B0 + (size_t)n0g * K;            Cp = C0; ldc = ldc0; c0 = n0g; }
    else              { Bsrc = B1 + (size_t)(n0g - nsplit) * K; Cp = C1; ldc = ldc1; c0 = n0g - nsplit; }

    const int arow = tid >> 1;        // 0..127 (tile row for staging)
    const int kh   = (tid & 1) << 4;  // 0 or 16 (k half)
    const float* Ag = A    + (size_t)(m0 + arow) * K + kh;
    const float* Bg = Bsrc + (size_t)arow * K + kh;

    const int lane = tid & 63;
    const int wm   = ((tid >> 6) >> 1) * 64;   // wave m-offset
    const int wn   = ((tid >> 6) & 1) * 64;    // wave n-offset
    const int lrow = lane & 15;
    const int quad = lane >> 4;

    f4v acc[4][4];
    #pragma unroll
    for (int i = 0; i < 4; ++i)
      #pragma unroll
      for (int j = 0; j < 4; ++j) acc[i][j] = (f4v){0.f, 0.f, 0.f, 0.f};

    // prefetch tile 0 (16 floats each from A and B)
    float4 a0 = *(const float4*)(Ag + 0);
    float4 a1 = *(const float4*)(Ag + 4);
    float4 a2 = *(const float4*)(Ag + 8);
    float4 a3 = *(const float4*)(Ag + 12);
    float4 b0 = *(const float4*)(Bg + 0);
    float4 b1 = *(const float4*)(Bg + 4);
    float4 b2 = *(const float4*)(Bg + 8);
    float4 b3 = *(const float4*)(Bg + 12);

    for (int kt = 0; kt < K; kt += 32) {
        __syncthreads();
        s8v p0, p1;
        p0[0]=(short)f2bf(a0.x); p0[1]=(short)f2bf(a0.y); p0[2]=(short)f2bf(a0.z); p0[3]=(short)f2bf(a0.w);
        p0[4]=(short)f2bf(a1.x); p0[5]=(short)f2bf(a1.y); p0[6]=(short)f2bf(a1.z); p0[7]=(short)f2bf(a1.w);
        p1[0]=(short)f2bf(a2.x); p1[1]=(short)f2bf(a2.y); p1[2]=(short)f2bf(a2.z); p1[3]=(short)f2bf(a2.w);
        p1[4]=(short)f2bf(a3.x); p1[5]=(short)f2bf(a3.y); p1[6]=(short)f2bf(a3.z); p1[7]=(short)f2bf(a3.w);
        *(s8v*)&As[arow * 40 + kh]     = p0;
        *(s8v*)&As[arow * 40 + kh + 8] = p1;
        p0[0]=(short)f2bf(b0.x); p0[1]=(short)f2bf(b0.y); p0[2]=(short)f2bf(b0.z); p0[3]=(short)f2bf(b0.w);
        p0[4]=(short)f2bf(b1.x); p0[5]=(short)f2bf(b1.y); p0[6]=(short)f2bf(b1.z); p0[7]=(short)f2bf(b1.w);
        p1[0]=(short)f2bf(b2.x); p1[1]=(short)f2bf(b2.y); p1[2]=(short)f2bf(b2.z); p1[3]=(short)f2bf(b2.w);
        p1[4]=(short)f2bf(b3.x); p1[5]=(short)f2bf(b3.y); p1[6]=(short)f2bf(b3.z); p1[7]=(short)f2bf(b3.w);
        *(s8v*)&Bs[arow * 40 + kh]     = p0;
        *(s8v*)&Bs[arow * 40 + kh + 8] = p1;
        __syncthreads();

        if (kt + 32 < K) {   // prefetch next while mfma runs
            a0 = *(const float4*)(Ag + kt + 32);
            a1 = *(const float4*)(Ag + kt + 36);
            a2 = *(const float4*)(Ag + kt + 40);
            a3 = *(const float4*)(Ag + kt + 44);
            b0 = *(const float4*)(Bg + kt + 32);
            b1 = *(const float4*)(Bg + kt + 36);
            b2 = *(const float4*)(Bg + kt + 40);
            b3 = *(const float4*)(Bg + kt + 44);
        }

        s8v af[4], bf[4];
        #pragma unroll
        for (int i = 0; i < 4; ++i)
            af[i] = *(const s8v*)&As[(wm + i * 16 + lrow) * 40 + quad * 8];
        #pragma unroll
        for (int j = 0; j < 4; ++j)
            bf[j] = *(const s8v*)&Bs[(wn + j * 16 + lrow) * 40 + quad * 8];
        #pragma unroll
        for (int i = 0; i < 4; ++i)
          #pragma unroll
          for (int j = 0; j < 4; ++j)
              acc[i][j] = __builtin_amdgcn_mfma_f32_16x16x32_bf16(af[i], bf[j], acc[i][j], 0, 0, 0);
    }

    float sc = 1.0f;
    if (mode == 1) sc = sptr[0];
    else if (mode == 2) { float s = sptr[0]; sc = 1.0f / (s * s); }

    // C/D layout: col = lane&15, row = quad*4 + reg  [m89-verified]
    #pragma unroll
    for (int i = 0; i < 4; ++i)
      #pragma unroll
      for (int j = 0; j < 4; ++j) {
        const int col = c0 + wn + j * 16 + lrow;
        #pragma unroll
        for (int r = 0; r < 4; ++r) {
            const int row = m0 + wm + i * 16 + quad * 4 + r;
            Cp[(size_t)row * ldc + col] = acc[i][j][r] * sc;
        }
    }
}

// =====================================================================
// fp32 NT GEMM, 64x64 tile, BK=32 — precision-critical grams only.
// =====================================================================
__global__ __launch_bounds__(256, 4) void gemm_nt_64(
    const float* __restrict__ A, const float* __restrict__ Bm,
    float* __restrict__ C, int K, int ldc)
{
    __shared__ float As[32][68];
    __shared__ float Bs[32][68];
    const int tid = threadIdx.x;
    const int m0 = blockIdx.y * 64;
    const int n0 = blockIdx.x * 64;
    const int lr = tid >> 3;
    const int lq = (tid & 7) << 2;
    const float* Ag = A  + (size_t)(m0 + lr) * K + lq;
    const float* Bg = Bm + (size_t)(n0 + lr) * K + lq;
    const int tx = tid & 15;
    const int ty = tid >> 4;

    float acc[4][4];
    #pragma unroll
    for (int i = 0; i < 4; ++i)
      #pragma unroll
      for (int j = 0; j < 4; ++j) acc[i][j] = 0.f;

    float4 a0 = *(const float4*)(Ag);
    float4 a1 = *(const float4*)(Ag + (size_t)32 * K);
    float4 b0 = *(const float4*)(Bg);
    float4 b1 = *(const float4*)(Bg + (size_t)32 * K);

    for (int kt = 0; kt < K; kt += 32) {
        __syncthreads();
        As[lq+0][lr]    = a0.x; As[lq+1][lr]    = a0.y; As[lq+2][lr]    = a0.z; As[lq+3][lr]    = a0.w;
        As[lq+0][32+lr] = a1.x; As[lq+1][32+lr] = a1.y; As[lq+2][32+lr] = a1.z; As[lq+3][32+lr] = a1.w;
        Bs[lq+0][lr]    = b0.x; Bs[lq+1][lr]    = b0.y; Bs[lq+2][lr]    = b0.z; Bs[lq+3][lr]    = b0.w;
        Bs[lq+0][32+lr] = b1.x; Bs[lq+1][32+lr] = b1.y; Bs[lq+2][32+lr] = b1.z; Bs[lq+3][32+lr] = b1.w;
        __syncthreads();
        if (kt + 32 < K) {
            a0 = *(const float4*)(Ag + kt + 32);
            a1 = *(const float4*)(Ag + kt + 32 + (size_t)32 * K);
            b0 = *(const float4*)(Bg + kt + 32);
            b1 = *(const float4*)(Bg + kt + 32 + (size_t)32 * K);
        }
        #pragma unroll
        for (int k = 0; k < 32; ++k) {
            float4 av = *(const float4*)&As[k][ty*4];
            float4 bv = *(const float4*)&Bs[k][tx*4];
            float avf[4] = {av.x,av.y,av.z,av.w};
            float bvf[4] = {bv.x,bv.y,bv.z,bv.w};
            #pragma unroll
            for (int i = 0; i < 4; ++i)
              #pragma unroll
              for (int j = 0; j < 4; ++j)
                  acc[i][j] = fmaf(avf[i], bvf[j], acc[i][j]);
        }
    }
    #pragma unroll
    for (int i = 0; i < 4; ++i) {
        const int row = m0 + ty*4 + i;
        float4 v;
        v.x = acc[i][0]; v.y = acc[i][1]; v.z = acc[i][2]; v.w = acc[i][3];
        *(float4*)(C + (size_t)row * ldc + n0 + tx*4) = v;
    }
}

// ---------------- trace of 1024x1024 (1 block) ----------------
__global__ void trace_diag(const float* __restrict__ A, float* __restrict__ out)
{
    __shared__ float red[256];
    const int tid = threadIdx.x;
    float s = 0.f;
    for (int i = tid; i < N_; i += 256) s += A[(size_t)i * (N_ + 1)];
    red[tid] = s; __syncthreads();
    for (int off = 128; off > 0; off >>= 1) {
        if (tid < off) red[tid] += red[tid + off];
        __syncthreads();
    }
    if (tid == 0) out[0] = red[0];
}

// ---- pick column with max diagonal (dominant-eigvec seed) ----
__global__ void pick_col(const float* __restrict__ P, float* __restrict__ v)
{
    __shared__ float sval[256];
    __shared__ int   sidx[256];
    __shared__ int   jstar;
    const int tid = threadIdx.x;
    float best = -1.f; int bidx = 0;
    for (int i = tid; i < N_; i += 256) {
        float d = P[(size_t)i * (N_ + 1)];
        if (d > best) { best = d; bidx = i; }
    }
    sval[tid] = best; sidx[tid] = bidx; __syncthreads();
    for (int off = 128; off > 0; off >>= 1) {
        if (tid < off && sval[tid + off] > sval[tid]) {
            sval[tid] = sval[tid + off]; sidx[tid] = sidx[tid + off];
        }
        __syncthreads();
    }
    if (tid == 0) jstar = sidx[0];
    __syncthreads();
    const int j = jstar;
    for (int i = tid; i < N_; i += 256) v[i] = P[(size_t)j * N_ + i];
}

// ---------------- w = G * v (one wave per row) ----------------
__global__ __launch_bounds__(256) void matvec_1024(
    const float* __restrict__ G, const float* __restrict__ v, float* __restrict__ w)
{
    const int row  = blockIdx.x * 4 + (threadIdx.x >> 6);
    const int lane = threadIdx.x & 63;
    const float* g = G + (size_t)row * N_;
    float s = 0.f;
    for (int j = lane; j < N_; j += 64) s += g[j] * v[j];
    #pragma unroll
    for (int off = 32; off > 0; off >>= 1) s += __shfl_down(s, off, 64);
    if (lane == 0) w[row] = s;
}

// ------- Rayleigh quotient -> inv_scale = 1/max(sigma,1) -------
__global__ void rq_scale(const float* __restrict__ w1, const float* __restrict__ w2,
                         float* __restrict__ slot)
{
    __shared__ float r11[256];
    __shared__ float r12[256];
    const int tid = threadIdx.x;
    float d11 = 0.f, d12 = 0.f;
    for (int i = tid; i < N_; i += 256) {
        float a = w1[i], b = w2[i];
        d11 = fmaf(a, a, d11);
        d12 = fmaf(a, b, d12);
    }
    r11[tid] = d11; r12[tid] = d12; __syncthreads();
    for (int off = 128; off > 0; off >>= 1) {
        if (tid < off) { r11[tid] += r11[tid + off]; r12[tid] += r12[tid + off]; }
        __syncthreads();
    }
    if (tid == 0) {
        float lam = r12[0] / fmaxf(r11[0], 1e-30f);
        float sig = sqrtf(fmaxf(lam, 0.f));
        slot[0] = 1.0f / fmaxf(sig, 1.0f);
    }
}

// ---------------- fast elementwise math (hw v_exp/v_log) ----------------
__device__ __forceinline__ float fast_sp(float x)   // softplus
{
    return fmaxf(x, 0.f) + __logf(1.0f + __expf(-fabsf(x)));
}
__device__ __forceinline__ float fast_tanh(float x)
{
    float e = __expf(2.0f * fabsf(x));
    float t = 1.0f - 2.0f / (e + 1.0f);
    return copysignf(t, x);
}

__device__ __forceinline__ void abc_math(
    float dr, float br, float cr, float uval,
    float alpha, float db, float sgain,
    float* pa, float* pbu, float* pc)
{
    float delta = fast_sp(dr + db);
    float a = fminf(__expf(-delta * alpha), 1.0f - 1e-4f);
    float b = fast_tanh(br);
    float c = fast_tanh(cr);
    float p = fmaf(a, a, c * c);
    float r = b * b;
    float q = a * b;
    float pr = p - r;
    float disc = fmaf(pr, pr, 4.0f * q * q);
    float lam = 0.5f * (p + r + sqrtf(disc + 1e-12f));
    float sig = sqrtf(lam + 1e-12f);
    float inv = 1.0f / fmaxf(sig, 1.0f);
    a *= inv; b *= inv; c *= inv;
    *pa = a; *pc = c; *pbu = b * (sgain * uval);
}

// --------- scan phase 1 (per stripe): per-chunk composite ---------
__global__ __launch_bounds__(256) void scan_phase1(
    const float* __restrict__ rawS, const float* __restrict__ usS,
    const float* __restrict__ bp, const float* __restrict__ dbias,
    const float* __restrict__ alog, const float* __restrict__ lgam,
    const float* __restrict__ inv_sin,
    float* __restrict__ agg_a, float* __restrict__ agg_b, int r0)
{
    const int gid = blockIdx.x * 256 + threadIdx.x;   // [0, (SROWS_/CL_)*N_)
    const int n   = gid & (N_ - 1);
    const int cl  = gid >> 10;
    const int gchunk = (r0 >> 6) + cl;

    const float alpha = fast_sp(alog[n]);
    const float db    = dbias[n];
    const float bpd   = bp[n];
    const float bpb   = bp[N_ + n];
    const float bpc   = bp[2*N_ + n];
    const float sgain = __expf(lgam[0]) * inv_sin[0];

    float Ap = 1.f, Bc = 0.f;
    size_t base  = (size_t)(cl * CL_) * K3_ + n;
    size_t ubase = (size_t)(cl * CL_) * N_  + n;
    for (int j = 0; j < CL_; ++j) {
        float dr = rawS[base]        + bpd;
        float br = rawS[base + N_]   + bpb;
        float cr = rawS[base + 2*N_] + bpc;
        float uv = usS[ubase];
        float a, bu, cv;
        abc_math(dr, br, cr, uv, alpha, db, sgain, &a, &bu, &cv);
        Bc = fmaf(a, Bc, bu);
        Ap *= a;
        base += K3_; ubase += N_;
    }
    agg_a[(size_t)gchunk * N_ + n] = Ap;
    agg_b[(size_t)gchunk * N_ + n] = Bc;
}

// --------- scan phase 2: exclusive scan over chunk aggregates ---------
__global__ void scan_phase2(const float* __restrict__ agg_a,
                            const float* __restrict__ agg_b,
                            float* __restrict__ pref)
{
    const int gid = blockIdx.x * 256 + threadIdx.x;   // 0..B*N-1
    const int n = gid & (N_ - 1);
    const int b = gid >> 10;
    float z = 0.f;
    size_t idx = (size_t)(b * (T_/CL_)) * N_ + n;
    for (int c = 0; c < T_/CL_; ++c) {
        pref[idx] = z;
        z = fmaf(agg_a[idx], z, agg_b[idx]);
        idx += N_;
    }
}

// --------- scan phase 3 (per stripe): replay with carry, y_hat over usS ---------
__global__ __launch_bounds__(256) void scan_phase3(
    const float* __restrict__ rawS, float* __restrict__ usS,
    const float* __restrict__ bp, const float* __restrict__ dbias,
    const float* __restrict__ alog, const float* __restrict__ lgam,
    const float* __restrict__ inv_sin, const float* __restrict__ pref, int r0)
{
    const int gid = blockIdx.x * 256 + threadIdx.x;
    const int n   = gid & (N_ - 1);
    const int cl  = gid >> 10;
    const int gchunk = (r0 >> 6) + cl;

    const float alpha = fast_sp(alog[n]);
    const float db    = dbias[n];
    const float bpd   = bp[n];
    const float bpb   = bp[N_ + n];
    const float bpc   = bp[2*N_ + n];
    const float sgain = __expf(lgam[0]) * inv_sin[0];

    float z = pref[(size_t)gchunk * N_ + n];
    size_t base  = (size_t)(cl * CL_) * K3_ + n;
    size_t ubase = (size_t)(cl * CL_) * N_  + n;
    for (int j = 0; j < CL_; ++j) {
        float dr = rawS[base]        + bpd;
        float br = rawS[base + N_]   + bpb;
        float cr = rawS[base + 2*N_] + bpc;
        float uv = usS[ubase];
        float a, bu, cv;
        abc_math(dr, br, cr, uv, alpha, db, sgain, &a, &bu, &cv);
        usS[ubase] = cv * z;
        z = fmaf(a, z, bu);
        base += K3_; ubase += N_;
    }
}

// =====================================================================
extern "C" void kernel_launch(void* const* d_in, const int* in_sizes, int n_in,
                              void* d_out, int out_size, void* d_ws, size_t ws_size,
                              hipStream_t stream)
{
    (void)in_sizes; (void)n_in;
    const float* u     = (const float*)d_in[0];
    const float* W_in  = (const float*)d_in[1];
    const float* W_out = (const float*)d_in[2];
    const float* Wp    = (const float*)d_in[3];
    const float* bp    = (const float*)d_in[4];
    const float* alog  = (const float*)d_in[5];
    const float* dbias = (const float*)d_in[6];
    const float* lgam  = (const float*)d_in[7];
    float* y = (float*)d_out;

    if (ws_size < (size_t)REQ_FLOATS * sizeof(float)) {
        zero_out<<<(out_size + 255) / 256, dim3(256), 0, stream>>>(y, out_size);
        return;
    }

    float* ws    = (float*)d_ws;
    float* rawS  = ws + OFF_RAWS;
    float* usS   = ws + OFF_USS;
    float* G0    = ws + OFF_G0;
    float* Pb    = ws + OFF_P;
    float* Qb    = ws + OFF_Q;
    float* agg_a = ws + OFF_AGA;
    float* agg_b = ws + OFF_AGB;
    float* pref  = ws + OFF_PRE;
    float* v0    = ws + OFF_V0;
    float* w1    = ws + OFF_W1;
    float* w2    = ws + OFF_W2;
    float* scal  = ws + OFF_SC;

    const dim3 blk(256);
    const int BIG = 1 << 30;

    // ---- spectral norms: fp32 gram + 8 bf16 trace-normalized squarings + fp32 RQ ----
    auto sigma_pipeline = [&](const float* W, float* slot) {
        gemm_nt_64<<<dim3(16, 16), blk, 0, stream>>>(W, W, G0, 1024, 1024);
        const float* src = G0;
        float* dst = Pb;
        for (int i = 0; i < 8; ++i) {
            trace_diag<<<1, blk, 0, stream>>>(src, scal + 0);
            gemm_bf16_nt<<<dim3(8, 8), blk, 0, stream>>>(
                src, src, nullptr, dst, nullptr, 1024, N_, 0, BIG, scal + 0, 2);
            src = dst;
            dst = (dst == Pb) ? Qb : Pb;
        }
        pick_col<<<1, blk, 0, stream>>>(src, v0);
        matvec_1024<<<256, blk, 0, stream>>>(G0, v0, w1);
        matvec_1024<<<256, blk, 0, stream>>>(G0, w1, w2);
        rq_scale<<<1, blk, 0, stream>>>(w1, w2, slot);
    };
    sigma_pipeline(W_in,  scal + 1);   // inv_scale_in
    sigma_pipeline(W_out, scal + 2);   // inv_scale_out

    const int sblocks = (SROWS_/CL_) * N_ / 256;   // 128 blocks per stripe

    // ---- pass A: fused (W_in|Wp) bf16 gemm -> usS+rawS, then chunk aggregates ----
    for (int s = 0; s < NSTRIPE_; ++s) {
        const int r0 = s * SROWS_;
        gemm_bf16_nt<<<dim3(32, SROWS_/128), blk, 0, stream>>>(
            u + (size_t)r0 * DD_, W_in, Wp, usS, rawS,
            1024, N_, K3_, N_, nullptr, 0);
        scan_phase1<<<sblocks, blk, 0, stream>>>(rawS, usS, bp, dbias, alog, lgam,
                                                 scal + 1, agg_a, agg_b, r0);
    }

    // ---- chunk-prefix scan (per batch) ----
    scan_phase2<<<(B_*N_)/256, blk, 0, stream>>>(agg_a, agg_b, pref);

    // ---- pass B: recompute, replay scan, y stripe out ----
    for (int s = 0; s < NSTRIPE_; ++s) {
        const int r0 = s * SROWS_;
        gemm_bf16_nt<<<dim3(32, SROWS_/128), blk, 0, stream>>>(
            u + (size_t)r0 * DD_, W_in, Wp, usS, rawS,
            1024, N_, K3_, N_, nullptr, 0);
        scan_phase3<<<sblocks, blk, 0, stream>>>(rawS, usS, bp, dbias, alog, lgam,
                                                 scal + 1, pref, r0);
        gemm_bf16_nt<<<dim3(8, SROWS_/128), blk, 0, stream>>>(
            usS, W_out, nullptr, y + (size_t)r0 * N_, nullptr,
            1024, N_, 0, BIG, scal + 2, 1);
    }
}

// Round 5
// 1134.428 us; speedup vs baseline: 6.6234x; 2.3016x over previous
//
#include <hip/hip_runtime.h>

// ---------------- problem dims (fixed by setup_inputs) ----------------
#define B_    4
#define T_    4096
#define DD_   1024
#define N_    1024
#define K3_   3072
#define M_    16384      // B_*T_
#define CL_   16         // scan chunk length (time steps)
#define SROWS_ 2048      // stripe rows (one stripe = half a batch, aligned)
#define NSTRIPE_ (M_/SROWS_)     // 8
#define CPS_  (SROWS_/CL_)       // 128 chunks per stripe
#define MEG_  1048576

// ---------------- ws layout (float offsets), total ~47.6 MiB ----------------
// rawS (24 MiB) is aliased by the sigma phase: G0 | P | Q (2 z-slices each).
#define OFF_RAWS  ((size_t)0)                        // 6M f   (24 MiB)
#define OFF_USS   ((size_t)6*MEG_)                   // 2M f   (8 MiB)  [sigma alias: Sbf 2M shorts]
#define OFF_UBF   ((size_t)8*MEG_)                   // 1M f = 2M shorts (u stripe bf16; later y_hat bf16)
#define OFF_WCAT  ((size_t)9*MEG_)                   // 2M f = 4M shorts (W_in rows then Wp rows)
#define OFF_WOUTB ((size_t)11*MEG_)                  // 512K f = 1M shorts
#define OFF_AGA   (OFF_WOUTB + 524288)               // 128K f
#define OFF_AGB   (OFF_AGA + 131072)
#define OFF_PRE   (OFF_AGB + 131072)
#define OFF_CARRY (OFF_PRE + 131072)                 // 4096 f
#define OFF_V0    (OFF_CARRY + 4096)                 // 2048 f (2 z)
#define OFF_W1    (OFF_V0 + 2048)
#define OFF_W2    (OFF_W1 + 2048)
#define OFF_TR    (OFF_W2 + 2048)                    // 16 f: tr[round][z]
#define OFF_SCAL  (OFF_TR + 16)                      // [0]=inv_in, [1]=inv_out
#define REQ_FLOATS (OFF_SCAL + 16)

typedef short s8v __attribute__((ext_vector_type(8)));   // 8 bf16 (4 VGPRs)
typedef float f4v __attribute__((ext_vector_type(4)));   // MFMA acc

typedef __attribute__((address_space(3))) unsigned int       lds_u32;
typedef const __attribute__((address_space(1))) unsigned int glb_u32;

__device__ __forceinline__ void gload_lds16(const void* g, void* l)
{
    __builtin_amdgcn_global_load_lds((glb_u32*)g, (lds_u32*)l, 16, 0, 0);
}

// fp32 -> bf16 round-to-nearest-even
__device__ __forceinline__ unsigned short f2bf(float f)
{
    unsigned u = __float_as_uint(f);
    u += 0x7FFFu + ((u >> 16) & 1u);
    return (unsigned short)(u >> 16);
}

// ---------------- fallback: zero a float buffer ----------------
__global__ void zero_out(float* __restrict__ y, int n)
{
    int i = blockIdx.x * 256 + threadIdx.x;
    if (i < n) y[i] = 0.f;
}

// ---------------- one-time weight conversion to bf16 ----------------
__global__ void cvt_weights(const float* __restrict__ Win, const float* __restrict__ Wp,
                            const float* __restrict__ Wout,
                            unsigned short* __restrict__ Wcat,
                            unsigned short* __restrict__ Woutb)
{
    int i = blockIdx.x * 256 + threadIdx.x;        // 0 .. 5M-1
    if (i < 1048576)       Wcat[i] = f2bf(Win[i]);
    else if (i < 4194304)  Wcat[i] = f2bf(Wp[i - 1048576]);
    else if (i < 5242880)  Woutb[i - 4194304] = f2bf(Wout[i - 4194304]);
}

// ---------------- per-stripe u conversion ----------------
__global__ void cvt_u(const float* __restrict__ src, unsigned short* __restrict__ dst)
{
    int i = blockIdx.x * 256 + threadIdx.x;        // 0 .. 2M-1
    dst[i] = f2bf(src[i]);
}

// ------- sigma: normalize by trace (device value) and convert to bf16 -------
__global__ void cvt_norm(const float* __restrict__ S, unsigned short* __restrict__ Sbf,
                         const float* __restrict__ trz)
{
    int i = blockIdx.x * 256 + threadIdx.x;        // 0 .. 2M-1 (2 z-slices of 1M)
    int z = i >> 20;
    float rs = 1.0f / trz[z];
    Sbf[i] = f2bf(S[i] * rs);
}

// =====================================================================
// Pure-bf16 MFMA NT GEMM, 128x128 tile, BK=32, 256 thr (4 waves 2x2,
// each 64x64 via 4x4 mfma_16x16x32). global_load_lds dwordx4 staging,
// unpadded LDS [row][32] bf16. Dual-output column split at nsplit.
// z-batched via blockIdx.z with element strides zsA/zsB (shorts), zsC
// (floats). mode: 0 plain, 1 scale by sptr[0], 3 trace-atomic to trc[z].
// =====================================================================
__global__ __launch_bounds__(256, 2) void gemm_bf16(
    const unsigned short* __restrict__ A,
    const unsigned short* __restrict__ B0, const unsigned short* __restrict__ B1,
    float* __restrict__ C0, float* __restrict__ C1,
    int K, int ldc0, int ldc1, int nsplit,
    long zsA, long zsB, long zsC,
    const float* __restrict__ sptr, float* __restrict__ trc, int mode)
{
    __shared__ __align__(16) unsigned short As[128 * 32];
    __shared__ __align__(16) unsigned short Bs[128 * 32];
    const int tid = threadIdx.x;
    const int z   = blockIdx.z;
    const int m0  = blockIdx.y * 128;
    const int n0g = blockIdx.x * 128;

    const unsigned short* Az = A + (size_t)z * zsA;
    const unsigned short* Bsrc; float* Cp; int ldc; int c0;
    if (n0g < nsplit) {
        Bsrc = B0 + (size_t)z * zsB + (size_t)n0g * K;
        Cp = C0 + (size_t)z * zsC; ldc = ldc0; c0 = n0g;
    } else {
        Bsrc = B1 + (size_t)(n0g - nsplit) * K;
        Cp = C1; ldc = ldc1; c0 = n0g - nsplit;
    }

    const int lane = tid & 63;
    const int w    = tid >> 6;          // wave 0..3
    const int wm   = (w >> 1) * 64;
    const int wn   = (w & 1) * 64;
    const int lrow = lane & 15;
    const int quad = lane >> 4;

    // staging: wave w covers tile rows [w*32, w*32+32); two 16-row wave-loads
    // per matrix. lane -> row w*32 + q*16 + (lane>>2), 16B granule (lane&3)*8.
    const int srow = (lane >> 2);
    const int scol = (lane & 3) * 8;
    const unsigned short* Agl0 = Az   + (size_t)(m0 + w*32 + srow) * K + scol;
    const unsigned short* Agl1 = Agl0 + (size_t)16 * K;
    const unsigned short* Bgl0 = Bsrc + (size_t)(w*32 + srow) * K + scol;
    const unsigned short* Bgl1 = Bgl0 + (size_t)16 * K;
    unsigned short* lA0 = &As[(w*32     ) * 32];
    unsigned short* lA1 = &As[(w*32 + 16) * 32];
    unsigned short* lB0 = &Bs[(w*32     ) * 32];
    unsigned short* lB1 = &Bs[(w*32 + 16) * 32];

    f4v acc[4][4];
    #pragma unroll
    for (int i = 0; i < 4; ++i)
      #pragma unroll
      for (int j = 0; j < 4; ++j) acc[i][j] = (f4v){0.f, 0.f, 0.f, 0.f};

    for (int kt = 0; kt < K; kt += 32) {
        __syncthreads();                       // prev iter's LDS reads done
        gload_lds16(Agl0 + kt, lA0);
        gload_lds16(Agl1 + kt, lA1);
        gload_lds16(Bgl0 + kt, lB0);
        gload_lds16(Bgl1 + kt, lB1);
        __syncthreads();                       // drains vmcnt before barrier

        s8v af[4], bf[4];
        #pragma unroll
        for (int i = 0; i < 4; ++i)
            af[i] = *(const s8v*)&As[(wm + i*16 + lrow) * 32 + quad * 8];
        #pragma unroll
        for (int j = 0; j < 4; ++j)
            bf[j] = *(const s8v*)&Bs[(wn + j*16 + lrow) * 32 + quad * 8];
        #pragma unroll
        for (int i = 0; i < 4; ++i)
          #pragma unroll
          for (int j = 0; j < 4; ++j)
              acc[i][j] = __builtin_amdgcn_mfma_f32_16x16x32_bf16(af[i], bf[j], acc[i][j], 0, 0, 0);
    }

    float sc = (mode == 1) ? sptr[0] : 1.0f;

    // C/D layout: col = lane&15, row = quad*4 + reg  [m89-verified]
    #pragma unroll
    for (int i = 0; i < 4; ++i)
      #pragma unroll
      for (int j = 0; j < 4; ++j) {
        const int col = c0 + wn + j * 16 + lrow;
        #pragma unroll
        for (int r = 0; r < 4; ++r) {
            const int row = m0 + wm + i * 16 + quad * 4 + r;
            Cp[(size_t)row * ldc + col] = acc[i][j][r] * sc;
        }
    }

    if (mode == 3 && m0 == n0g && wm == wn && (lrow >> 2) == quad) {
        const int r = lrow & 3;        // row == col within each i==j block
        float d = acc[0][0][r] + acc[1][1][r] + acc[2][2][r] + acc[3][3][r];
        atomicAdd(trc + z, d);
    }
}

// =====================================================================
// fp32 NT gram, 64x64 tile, BK=32, z-batched (z: A0 or A1), C = W W^T.
// Trace accumulated into trc[z] via atomics (diagonal tiles).
// =====================================================================
__global__ __launch_bounds__(256, 4) void gemm_gram_f32(
    const float* __restrict__ A0, const float* __restrict__ A1,
    float* __restrict__ C, long zsC, float* __restrict__ trc)
{
    __shared__ float As[32][68];
    __shared__ float Bs[32][68];
    const int tid = threadIdx.x;
    const int z = blockIdx.z;
    const float* A = z ? A1 : A0;
    const int m0 = blockIdx.y * 64;
    const int n0 = blockIdx.x * 64;
    const int lr = tid >> 3;
    const int lq = (tid & 7) << 2;
    const float* Ag = A + (size_t)(m0 + lr) * 1024 + lq;
    const float* Bg = A + (size_t)(n0 + lr) * 1024 + lq;
    const int tx = tid & 15;
    const int ty = tid >> 4;

    float acc[4][4];
    #pragma unroll
    for (int i = 0; i < 4; ++i)
      #pragma unroll
      for (int j = 0; j < 4; ++j) acc[i][j] = 0.f;

    float4 a0 = *(const float4*)(Ag);
    float4 a1 = *(const float4*)(Ag + (size_t)32 * 1024);
    float4 b0 = *(const float4*)(Bg);
    float4 b1 = *(const float4*)(Bg + (size_t)32 * 1024);

    for (int kt = 0; kt < 1024; kt += 32) {
        __syncthreads();
        As[lq+0][lr]    = a0.x; As[lq+1][lr]    = a0.y; As[lq+2][lr]    = a0.z; As[lq+3][lr]    = a0.w;
        As[lq+0][32+lr] = a1.x; As[lq+1][32+lr] = a1.y; As[lq+2][32+lr] = a1.z; As[lq+3][32+lr] = a1.w;
        Bs[lq+0][lr]    = b0.x; Bs[lq+1][lr]    = b0.y; Bs[lq+2][lr]    = b0.z; Bs[lq+3][lr]    = b0.w;
        Bs[lq+0][32+lr] = b1.x; Bs[lq+1][32+lr] = b1.y; Bs[lq+2][32+lr] = b1.z; Bs[lq+3][32+lr] = b1.w;
        __syncthreads();
        if (kt + 32 < 1024) {
            a0 = *(const float4*)(Ag + kt + 32);
            a1 = *(const float4*)(Ag + kt + 32 + (size_t)32 * 1024);
            b0 = *(const float4*)(Bg + kt + 32);
            b1 = *(const float4*)(Bg + kt + 32 + (size_t)32 * 1024);
        }
        #pragma unroll
        for (int k = 0; k < 32; ++k) {
            float4 av = *(const float4*)&As[k][ty*4];
            float4 bv = *(const float4*)&Bs[k][tx*4];
            float avf[4] = {av.x,av.y,av.z,av.w};
            float bvf[4] = {bv.x,bv.y,bv.z,bv.w};
            #pragma unroll
            for (int i = 0; i < 4; ++i)
              #pragma unroll
              for (int j = 0; j < 4; ++j)
                  acc[i][j] = fmaf(avf[i], bvf[j], acc[i][j]);
        }
    }
    float* Cz = C + (size_t)z * zsC;
    #pragma unroll
    for (int i = 0; i < 4; ++i) {
        const int row = m0 + ty*4 + i;
        float4 v;
        v.x = acc[i][0]; v.y = acc[i][1]; v.z = acc[i][2]; v.w = acc[i][3];
        *(float4*)(Cz + (size_t)row * 1024 + n0 + tx*4) = v;
    }
    if (m0 == n0 && tx == ty) {
        float d = acc[0][0] + acc[1][1] + acc[2][2] + acc[3][3];
        atomicAdd(trc + z, d);
    }
}

// ---- pick column with max diagonal (dominant-eigvec seed), z=blockIdx.x ----
__global__ void pick_col(const float* __restrict__ Pall, float* __restrict__ vall)
{
    const float* P = Pall + (size_t)blockIdx.x * MEG_;
    float* v = vall + blockIdx.x * N_;
    __shared__ float sval[256];
    __shared__ int   sidx[256];
    __shared__ int   jstar;
    const int tid = threadIdx.x;
    float best = -1.f; int bidx = 0;
    for (int i = tid; i < N_; i += 256) {
        float d = P[(size_t)i * (N_ + 1)];
        if (d > best) { best = d; bidx = i; }
    }
    sval[tid] = best; sidx[tid] = bidx; __syncthreads();
    for (int off = 128; off > 0; off >>= 1) {
        if (tid < off && sval[tid + off] > sval[tid]) {
            sval[tid] = sval[tid + off]; sidx[tid] = sidx[tid + off];
        }
        __syncthreads();
    }
    if (tid == 0) jstar = sidx[0];
    __syncthreads();
    const int j = jstar;   // symmetric: row j == column j
    for (int i = tid; i < N_; i += 256) v[i] = P[(size_t)j * N_ + i];
}

// ---------------- w = G[z] * v[z] (one wave per row), z=blockIdx.y ----------
__global__ __launch_bounds__(256) void matvec_z(
    const float* __restrict__ Gall, const float* __restrict__ vall,
    float* __restrict__ wall)
{
    const int z = blockIdx.y;
    const float* G = Gall + (size_t)z * MEG_;
    const float* v = vall + z * N_;
    const int row  = blockIdx.x * 4 + (threadIdx.x >> 6);
    const int lane = threadIdx.x & 63;
    const float* g = G + (size_t)row * N_;
    float s = 0.f;
    for (int j = lane; j < N_; j += 64) s += g[j] * v[j];
    #pragma unroll
    for (int off = 32; off > 0; off >>= 1) s += __shfl_down(s, off, 64);
    if (lane == 0) wall[z * N_ + row] = s;
}

// ------- Rayleigh quotient -> inv_scale[z] = 1/max(sigma,1), z=blockIdx.x ----
__global__ void rq_scale(const float* __restrict__ w1a, const float* __restrict__ w2a,
                         float* __restrict__ slot)
{
    const int z = blockIdx.x;
    const float* w1 = w1a + z * N_;
    const float* w2 = w2a + z * N_;
    __shared__ float r11[256];
    __shared__ float r12[256];
    const int tid = threadIdx.x;
    float d11 = 0.f, d12 = 0.f;
    for (int i = tid; i < N_; i += 256) {
        float a = w1[i], b = w2[i];
        d11 = fmaf(a, a, d11);
        d12 = fmaf(a, b, d12);
    }
    r11[tid] = d11; r12[tid] = d12; __syncthreads();
    for (int off = 128; off > 0; off >>= 1) {
        if (tid < off) { r11[tid] += r11[tid + off]; r12[tid] += r12[tid + off]; }
        __syncthreads();
    }
    if (tid == 0) {
        float lam = r12[0] / fmaxf(r11[0], 1e-30f);
        float sig = sqrtf(fmaxf(lam, 0.f));
        slot[z] = 1.0f / fmaxf(sig, 1.0f);
    }
}

// ---------------- fast elementwise math (hw v_exp/v_log) ----------------
__device__ __forceinline__ float fast_sp(float x)   // softplus
{
    return fmaxf(x, 0.f) + __logf(1.0f + __expf(-fabsf(x)));
}
__device__ __forceinline__ float fast_tanh(float x)
{
    float e = __expf(2.0f * fabsf(x));
    float t = 1.0f - 2.0f / (e + 1.0f);
    return copysignf(t, x);
}

__device__ __forceinline__ void abc_math(
    float dr, float br, float cr, float uval,
    float alpha, float db, float sgain,
    float* pa, float* pbu, float* pc)
{
    float delta = fast_sp(dr + db);
    float a = fminf(__expf(-delta * alpha), 1.0f - 1e-4f);
    float b = fast_tanh(br);
    float c = fast_tanh(cr);
    float p = fmaf(a, a, c * c);
    float r = b * b;
    float q = a * b;
    float pr = p - r;
    float disc = fmaf(pr, pr, 4.0f * q * q);
    float lam = 0.5f * (p + r + sqrtf(disc + 1e-12f));
    float sig = sqrtf(lam + 1e-12f);
    float inv = 1.0f / fmaxf(sig, 1.0f);
    a *= inv; b *= inv; c *= inv;
    *pa = a; *pc = c; *pbu = b * (sgain * uval);
}

// --------- scan phase 1 (per stripe): per-chunk composite (CL=16) ---------
__global__ __launch_bounds__(256) void scan_phase1(
    const float* __restrict__ rawS, const float* __restrict__ usS,
    const float* __restrict__ bp, const float* __restrict__ dbias,
    const float* __restrict__ alog, const float* __restrict__ lgam,
    const float* __restrict__ inv_sin,
    float* __restrict__ agg_a, float* __restrict__ agg_b)
{
    const int gid = blockIdx.x * 256 + threadIdx.x;   // [0, CPS_*N_)
    const int n   = gid & (N_ - 1);
    const int cl  = gid >> 10;                        // local chunk 0..127

    const float alpha = fast_sp(alog[n]);
    const float db    = dbias[n];
    const float bpd   = bp[n];
    const float bpb   = bp[N_ + n];
    const float bpc   = bp[2*N_ + n];
    const float sgain = __expf(lgam[0]) * inv_sin[0];

    float Ap = 1.f, Bc = 0.f;
    size_t base  = (size_t)(cl * CL_) * K3_ + n;      // stripe-local
    size_t ubase = (size_t)(cl * CL_) * N_  + n;
    #pragma unroll 4
    for (int j = 0; j < CL_; ++j) {
        float dr = rawS[base]        + bpd;
        float br = rawS[base + N_]   + bpb;
        float cr = rawS[base + 2*N_] + bpc;
        float uv = usS[ubase];
        float a, bu, cv;
        abc_math(dr, br, cr, uv, alpha, db, sgain, &a, &bu, &cv);
        Bc = fmaf(a, Bc, bu);
        Ap *= a;
        base += K3_; ubase += N_;
    }
    agg_a[(size_t)cl * N_ + n] = Ap;
    agg_b[(size_t)cl * N_ + n] = Bc;
}

// --------- scan phase 2 (per stripe): chunk-prefix with inter-stripe carry ---
__global__ void scan_phase2s(const float* __restrict__ agg_a,
                             const float* __restrict__ agg_b,
                             float* __restrict__ pref, float* __restrict__ carry,
                             int bidx, int use_carry)
{
    const int n = blockIdx.x * 256 + threadIdx.x;     // 0..1023
    float z = use_carry ? carry[bidx * N_ + n] : 0.f;
    size_t idx = n;
    for (int c = 0; c < CPS_; ++c) {
        pref[idx] = z;
        z = fmaf(agg_a[idx], z, agg_b[idx]);
        idx += N_;
    }
    carry[bidx * N_ + n] = z;
}

// --------- scan phase 3 (per stripe): replay, write y_hat bf16 ---------
__global__ __launch_bounds__(256) void scan_phase3(
    const float* __restrict__ rawS, const float* __restrict__ usS,
    const float* __restrict__ bp, const float* __restrict__ dbias,
    const float* __restrict__ alog, const float* __restrict__ lgam,
    const float* __restrict__ inv_sin, const float* __restrict__ pref,
    unsigned short* __restrict__ yh)
{
    const int gid = blockIdx.x * 256 + threadIdx.x;
    const int n   = gid & (N_ - 1);
    const int cl  = gid >> 10;

    const float alpha = fast_sp(alog[n]);
    const float db    = dbias[n];
    const float bpd   = bp[n];
    const float bpb   = bp[N_ + n];
    const float bpc   = bp[2*N_ + n];
    const float sgain = __expf(lgam[0]) * inv_sin[0];

    float z = pref[(size_t)cl * N_ + n];
    size_t base  = (size_t)(cl * CL_) * K3_ + n;
    size_t ubase = (size_t)(cl * CL_) * N_  + n;
    #pragma unroll 4
    for (int j = 0; j < CL_; ++j) {
        float dr = rawS[base]        + bpd;
        float br = rawS[base + N_]   + bpb;
        float cr = rawS[base + 2*N_] + bpc;
        float uv = usS[ubase];
        float a, bu, cv;
        abc_math(dr, br, cr, uv, alpha, db, sgain, &a, &bu, &cv);
        yh[ubase] = f2bf(cv * z);          // y_hat[t] uses pre-update state
        z = fmaf(a, z, bu);
        base += K3_; ubase += N_;
    }
}

// =====================================================================
extern "C" void kernel_launch(void* const* d_in, const int* in_sizes, int n_in,
                              void* d_out, int out_size, void* d_ws, size_t ws_size,
                              hipStream_t stream)
{
    (void)in_sizes; (void)n_in;
    const float* u     = (const float*)d_in[0];
    const float* W_in  = (const float*)d_in[1];
    const float* W_out = (const float*)d_in[2];
    const float* Wp    = (const float*)d_in[3];
    const float* bp    = (const float*)d_in[4];
    const float* alog  = (const float*)d_in[5];
    const float* dbias = (const float*)d_in[6];
    const float* lgam  = (const float*)d_in[7];
    float* y = (float*)d_out;

    if (ws_size < (size_t)REQ_FLOATS * sizeof(float)) {
        zero_out<<<(out_size + 255) / 256, dim3(256), 0, stream>>>(y, out_size);
        return;
    }

    float* ws = (float*)d_ws;
    float*          rawS  = ws + OFF_RAWS;
    float*          usS   = ws + OFF_USS;
    unsigned short* ubf   = (unsigned short*)(ws + OFF_UBF);
    unsigned short* Wcat  = (unsigned short*)(ws + OFF_WCAT);
    unsigned short* Woutb = (unsigned short*)(ws + OFF_WOUTB);
    float* agg_a = ws + OFF_AGA;
    float* agg_b = ws + OFF_AGB;
    float* pref  = ws + OFF_PRE;
    float* carry = ws + OFF_CARRY;
    float* v0    = ws + OFF_V0;
    float* w1    = ws + OFF_W1;
    float* w2    = ws + OFF_W2;
    float* trbuf = ws + OFF_TR;
    float* scal  = ws + OFF_SCAL;
    // sigma-phase aliases (live only before stripe processing)
    float* G0  = rawS;                 // 2 x 1M f
    float* Pb  = rawS + 2*MEG_;
    float* Qb  = rawS + 4*MEG_;
    unsigned short* Sbf = (unsigned short*)usS;   // 2 x 1M shorts

    const dim3 blk(256);
    const int BIG = 1 << 30;

    zero_out<<<1, 64, 0, stream>>>(trbuf, 18);
    cvt_weights<<<20480, blk, 0, stream>>>(W_in, Wp, W_out, Wcat, Woutb);

    // ---- spectral norms: fp32 gram (z=2) + 6 bf16 squarings + fp32 RQ ----
    gemm_gram_f32<<<dim3(16, 16, 2), blk, 0, stream>>>(W_in, W_out, G0, MEG_, trbuf);
    float* Schain[7] = {G0, Pb, Qb, Pb, Qb, Pb, Qb};
    for (int r = 0; r < 6; ++r) {
        cvt_norm<<<8192, blk, 0, stream>>>(Schain[r], Sbf, trbuf + r*2);
        gemm_bf16<<<dim3(8, 8, 2), blk, 0, stream>>>(
            Sbf, Sbf, nullptr, Schain[r+1], nullptr,
            1024, 1024, 0, BIG, MEG_, MEG_, MEG_, nullptr, trbuf + (r+1)*2, 3);
    }
    pick_col<<<2, blk, 0, stream>>>(Schain[6], v0);
    matvec_z<<<dim3(256, 2), blk, 0, stream>>>(G0, v0, w1);
    matvec_z<<<dim3(256, 2), blk, 0, stream>>>(G0, w1, w2);
    rq_scale<<<2, blk, 0, stream>>>(w1, w2, scal);   // scal[0]=inv_in, scal[1]=inv_out

    // ---- single pass over stripes (sequential carry) ----
    for (int s = 0; s < NSTRIPE_; ++s) {
        const int r0 = s * SROWS_;
        cvt_u<<<8192, blk, 0, stream>>>(u + (size_t)r0 * DD_, ubf);
        // fused (W_in | Wp) gemm: cols < 1024 -> usS, cols >= 1024 -> rawS
        gemm_bf16<<<dim3(32, 16), blk, 0, stream>>>(
            ubf, Wcat, Wcat + (size_t)1024 * 1024, usS, rawS,
            1024, N_, K3_, 1024, 0, 0, 0, nullptr, nullptr, 0);
        scan_phase1<<<512, blk, 0, stream>>>(rawS, usS, bp, dbias, alog, lgam,
                                             scal, agg_a, agg_b);
        scan_phase2s<<<4, blk, 0, stream>>>(agg_a, agg_b, pref, carry, s >> 1, s & 1);
        scan_phase3<<<512, blk, 0, stream>>>(rawS, usS, bp, dbias, alog, lgam,
                                             scal, pref, ubf);   // y_hat bf16 -> ubf
        gemm_bf16<<<dim3(8, 16), blk, 0, stream>>>(
            ubf, Woutb, nullptr, y + (size_t)r0 * N_, nullptr,
            1024, N_, 0, BIG, 0, 0, 0, scal + 1, nullptr, 1);
    }
}